// Round 1
// 829.913 us; speedup vs baseline: 1.1949x; 1.1949x over previous
//
#include <hip/hip_runtime.h>
#include <hip/hip_bf16.h>
#include <stdint.h>

typedef __bf16 bf16;
typedef __bf16 bf16x8 __attribute__((ext_vector_type(8)));
typedef __bf16 bf16x4 __attribute__((ext_vector_type(4)));
typedef float  floatx4 __attribute__((ext_vector_type(4)));

#define DIMD 2048
#define BATB 4
#define SEQS 4096
#define MTOT (BATB*SEQS)   // 16384

#define BAR()   __builtin_amdgcn_s_barrier()
#define LGKM0() asm volatile("s_waitcnt lgkmcnt(0)" ::: "memory")
#define LGKM8() asm volatile("s_waitcnt lgkmcnt(8)" ::: "memory")
#define VMC6()  asm volatile("s_waitcnt vmcnt(6)" ::: "memory")
#define VMC0()  asm volatile("s_waitcnt vmcnt(0)" ::: "memory")
#define SCHED0() __builtin_amdgcn_sched_barrier(0)

__device__ __forceinline__ void gload_lds16(const bf16* g, bf16* l) {
    __builtin_amdgcn_global_load_lds(
        (const __attribute__((address_space(1))) void*)g,
        (__attribute__((address_space(3))) void*)l,
        16, 0, 0);
}

// ---------------- fp32 -> bf16 convert (weights) ----------------
__global__ __launch_bounds__(256) void f2bf_k(const float* __restrict__ src,
                                              bf16* __restrict__ dst, int n) {
    int i = (blockIdx.x * 256 + threadIdx.x) * 4;
    if (i >= n) return;
    float4 v = *(const float4*)&src[i];
    bf16x4 o;
    o[0] = (bf16)v.x; o[1] = (bf16)v.y; o[2] = (bf16)v.z; o[3] = (bf16)v.w;
    *(bf16x4*)&dst[i] = o;
}

// ---------------- RMSNorm: fp32 [M,2048] -> bf16 [M,2048] ----------------
__global__ __launch_bounds__(256) void rmsnorm_k(const float* __restrict__ x,
                                                 bf16* __restrict__ xn) {
    const int row = blockIdx.x;
    const int tid = threadIdx.x;
    const float* xr = x + (size_t)row * DIMD;
    float4 a = *(const float4*)&xr[tid * 8];
    float4 b = *(const float4*)&xr[tid * 8 + 4];
    float s = a.x*a.x + a.y*a.y + a.z*a.z + a.w*a.w
            + b.x*b.x + b.y*b.y + b.z*b.z + b.w*b.w;
    #pragma unroll
    for (int off = 32; off > 0; off >>= 1) s += __shfl_down(s, off);
    __shared__ float red[4];
    if ((tid & 63) == 0) red[tid >> 6] = s;
    __syncthreads();
    float tot = red[0] + red[1] + red[2] + red[3];
    float sc = rsqrtf(tot * (1.0f / DIMD) + 1.1920929e-07f);
    bf16x8 o;
    o[0] = (bf16)(a.x * sc); o[1] = (bf16)(a.y * sc);
    o[2] = (bf16)(a.z * sc); o[3] = (bf16)(a.w * sc);
    o[4] = (bf16)(b.x * sc); o[5] = (bf16)(b.y * sc);
    o[6] = (bf16)(b.z * sc); o[7] = (bf16)(b.w * sc);
    *(bf16x8*)&xn[(size_t)row * DIMD + tid * 8] = o;
}

// ---------------- gating + causal depthwise conv ----------------
__global__ __launch_bounds__(256) void gateconv_k(const bf16* __restrict__ h,
                                                  const float* __restrict__ cw,
                                                  const float* __restrict__ cb,
                                                  bf16* __restrict__ o,
                                                  const int* __restrict__ dil_p) {
    int gid = blockIdx.x * 256 + threadIdx.x;
    int m = gid >> 9;            // 512 groups of 4 dims per row
    int d = (gid & 511) << 2;
    int s = m & (SEQS - 1);
    int dil = dil_p[0];
    const bf16* hr = h + (size_t)m * (3 * DIMD);

    bf16x4 Cv = *(const bf16x4*)&hr[DIMD + d];
    bf16x4 B0 = *(const bf16x4*)&hr[d];
    bf16x4 Z0 = *(const bf16x4*)&hr[2 * DIMD + d];
    float y0[4], y1[4], y2[4];
    #pragma unroll
    for (int j = 0; j < 4; ++j) y0[j] = (float)B0[j] * (float)Z0[j];
    if (s >= dil) {
        const bf16* h1 = hr - (size_t)dil * 3 * DIMD;
        bf16x4 B1 = *(const bf16x4*)&h1[d];
        bf16x4 Z1 = *(const bf16x4*)&h1[2 * DIMD + d];
        #pragma unroll
        for (int j = 0; j < 4; ++j) y1[j] = (float)B1[j] * (float)Z1[j];
    } else {
        #pragma unroll
        for (int j = 0; j < 4; ++j) y1[j] = 0.0f;
    }
    if (s >= 2 * dil) {
        const bf16* h2 = hr - (size_t)(2 * dil) * 3 * DIMD;
        bf16x4 B2 = *(const bf16x4*)&h2[d];
        bf16x4 Z2 = *(const bf16x4*)&h2[2 * DIMD + d];
        #pragma unroll
        for (int j = 0; j < 4; ++j) y2[j] = (float)B2[j] * (float)Z2[j];
    } else {
        #pragma unroll
        for (int j = 0; j < 4; ++j) y2[j] = 0.0f;
    }
    bf16x4 ov;
    #pragma unroll
    for (int j = 0; j < 4; ++j) {
        float w0 = cw[(d + j) * 3 + 0];
        float w1 = cw[(d + j) * 3 + 1];
        float w2 = cw[(d + j) * 3 + 2];
        float conv = w0 * y2[j] + w1 * y1[j] + w2 * y0[j] + cb[d + j];
        ov[j] = (bf16)((float)Cv[j] * conv);
    }
    *(bf16x4*)&o[(size_t)m * DIMD + d] = ov;
}

// ---------------- NT bf16 GEMM: C[M,N] = A[M,K] * B[N,K]^T ----------------
// 256x256 tile, BK=64, 8 waves (2M x 4N), 8-phase schedule with counted vmcnt
// (m201 template). LDS 128 KiB double-buffered; chunk-XOR swizzle (slot =
// chunk ^ (row&7)) realized by pre-swizzling the global source so
// global_load_lds's linear lane placement lands the swizzle (0 bank conflicts,
// verified on the previous kernel).
//
// Per K-tile (4 phases): p0 reads all B frags + A-quad0 (12 ds_read_b128),
// p1 reads quads 1+2, p2 reads quad 3, p3 reads nothing. Staging (1 half-tile
// = 2 global_load_lds per phase, 2 K-tiles ahead): p0: Ah1(t+1)->other buf,
// p1: Bh0(t+2)->this buf, p2: Bh1(t+2), p3: Ah0(t+2). Every staged region's
// last ds_read retired at an earlier phase's lgkmcnt(0)+barrier.
// vmcnt(6) once per K-tile (at p3) leaves exactly {Bh0,Bh1,Ah0}(t+2) in
// flight and guarantees tile t+1 fully landed before its first read.
template<int RESID>
__global__ __launch_bounds__(512, 2) void gemm_bt(const bf16* __restrict__ A,
                                                  const bf16* __restrict__ B,
                                                  bf16* __restrict__ Hout,
                                                  float* __restrict__ Fout,
                                                  const float* __restrict__ resid,
                                                  const float* __restrict__ scale,
                                                  int M, int N, int K) {
    __shared__ __align__(16) bf16 smem[2][32768];   // [buf][A 16384 | B 16384]
    const int tid = threadIdx.x;
    const int wave = tid >> 6;
    const int lane = tid & 63;
    const int quad = lane >> 4;
    const int col16 = lane & 15;

    // bijective XCD-aware swizzle (nwg % 8 == 0 for both launches)
    const int nx   = (int)gridDim.x;
    const int nwg  = nx * (int)gridDim.y;
    const int orig = (int)blockIdx.y * nx + (int)blockIdx.x;
    const int lin  = (orig & 7) * (nwg >> 3) + (orig >> 3);
    const int n0 = (lin % nx) * 256;
    const int m0 = (lin / nx) * 256;

    const int wm = (wave >> 2) * 128;   // wave's 128-row half of the A tile
    const int wn = (wave & 3) * 64;     // wave's 64-row slice of the B tile

    // staging addressing: thread covers row srow (mod 64) chunk (tid&7);
    // fetches global chunk cs = c ^ (row&7) so linear LDS dest == swizzled
    const int srow = tid >> 3;                 // 0..63
    const int cs   = (tid & 7) ^ (srow & 7);
    const bf16* aSrc = A + (size_t)(m0 + srow) * K + cs * 8;
    const bf16* bSrc = B + (size_t)(n0 + srow) * K + cs * 8;
    const int stbase = wave * 512;             // wave-uniform LDS element base
    const size_t K64  = (size_t)K * 64;
    const size_t K128 = (size_t)K * 128;

    // ds_read addressing
    const int rsw = col16 & 7;
    const int ard = (wm + col16) * 64;
    const int brd = (wn + col16) * 64;
    const int sl0 = ((0 + quad) ^ rsw) * 8;    // k-slice 0 swizzled slot
    const int sl1 = ((4 + quad) ^ rsw) * 8;    // k-slice 1

    floatx4 acc[4][2][4];                      // [quad][mfrag][nfrag]
    #pragma unroll
    for (int q = 0; q < 4; ++q)
        #pragma unroll
        for (int f = 0; f < 2; ++f)
            #pragma unroll
            for (int n = 0; n < 4; ++n) acc[q][f][n] = (floatx4)0.0f;

    auto stage = [&](const bf16* src, bf16* dstBase, int t, int h) {
        const bf16* s = src + (size_t)h * K128 + (size_t)t * 64;
        bf16* d = dstBase + h * 8192 + stbase;
        gload_lds16(s, d);
        gload_lds16(s + K64, d + 4096);
    };
    auto lda2 = [&](bf16x8 (&q)[2][2], const bf16* Asb, int f0) {
        #pragma unroll
        for (int f = 0; f < 2; ++f) {
            const bf16* p = Asb + ard + (f0 + f) * (16 * 64);
            q[f][0] = *(const bf16x8*)(p + sl0);
            q[f][1] = *(const bf16x8*)(p + sl1);
        }
    };
    auto ldb4 = [&](bf16x8 (&q)[4][2], const bf16* Bsb) {
        #pragma unroll
        for (int n = 0; n < 4; ++n) {
            const bf16* p = Bsb + brd + n * (16 * 64);
            q[n][0] = *(const bf16x8*)(p + sl0);
            q[n][1] = *(const bf16x8*)(p + sl1);
        }
    };
    auto mm = [&](floatx4 (&ac)[2][4], bf16x8 (&a)[2][2], bf16x8 (&b)[4][2]) {
        __builtin_amdgcn_s_setprio(1);
        #pragma unroll
        for (int f = 0; f < 2; ++f)
            #pragma unroll
            for (int n = 0; n < 4; ++n) {
                ac[f][n] = __builtin_amdgcn_mfma_f32_16x16x32_bf16(a[f][0], b[n][0], ac[f][n], 0, 0, 0);
                ac[f][n] = __builtin_amdgcn_mfma_f32_16x16x32_bf16(a[f][1], b[n][1], ac[f][n], 0, 0, 0);
            }
        __builtin_amdgcn_s_setprio(0);
    };

    const int NT = K >> 6;   // 32 for K=2048

    // prologue: tile0 fully + tile1 {Bh0,Bh1,Ah0}; wait so tile0 landed
    stage(aSrc, smem[0],         0, 0);
    stage(aSrc, smem[0],         0, 1);
    stage(bSrc, smem[0] + 16384, 0, 0);
    stage(bSrc, smem[0] + 16384, 0, 1);
    stage(bSrc, smem[1] + 16384, 1, 0);
    stage(bSrc, smem[1] + 16384, 1, 1);
    stage(aSrc, smem[1],         1, 0);
    VMC6();
    BAR();

    for (int t = 0; t < NT - 2; ++t) {
        const int b = t & 1;
        const bf16* Asb = smem[b];
        const bf16* Bsb = smem[b] + 16384;
        bf16* Asw = smem[b];
        bf16* Bsw = smem[b] + 16384;
        bf16* Aso = smem[b ^ 1];
        bf16x8 bfr[4][2], A0[2][2], A1[2][2], A2[2][2], A3[2][2];
        // p0
        ldb4(bfr, Bsb);
        lda2(A0, Asb, 0);
        stage(aSrc, Aso, t + 1, 1);      // Ah1(t+1) -> other buf
        LGKM8();
        BAR(); LGKM0(); SCHED0();
        mm(acc[0], A0, bfr);
        BAR();
        // p1
        lda2(A1, Asb, 2);
        lda2(A2, Asb, 4);
        stage(bSrc, Bsw, t + 2, 0);      // Bh0(t+2) -> this buf
        BAR(); LGKM0(); SCHED0();
        mm(acc[1], A1, bfr);
        BAR();
        // p2
        lda2(A3, Asb, 6);
        stage(bSrc, Bsw, t + 2, 1);      // Bh1(t+2)
        BAR(); LGKM0(); SCHED0();
        mm(acc[2], A2, bfr);
        BAR();
        // p3
        stage(aSrc, Asw, t + 2, 0);      // Ah0(t+2)
        VMC6();
        BAR();
        mm(acc[3], A3, bfr);
        BAR();
    }
    {   // tile NT-2: stage only Ah1(NT-1); drain to 0 at p3
        const int t = NT - 2;
        const int b = t & 1;
        const bf16* Asb = smem[b];
        const bf16* Bsb = smem[b] + 16384;
        bf16* Aso = smem[b ^ 1];
        bf16x8 bfr[4][2], A0[2][2], A1[2][2], A2[2][2], A3[2][2];
        ldb4(bfr, Bsb);
        lda2(A0, Asb, 0);
        stage(aSrc, Aso, t + 1, 1);
        LGKM8();
        BAR(); LGKM0(); SCHED0();
        mm(acc[0], A0, bfr);
        BAR();
        lda2(A1, Asb, 2);
        lda2(A2, Asb, 4);
        BAR(); LGKM0(); SCHED0();
        mm(acc[1], A1, bfr);
        BAR();
        lda2(A3, Asb, 6);
        BAR(); LGKM0(); SCHED0();
        mm(acc[2], A2, bfr);
        BAR();
        VMC0();
        BAR();
        mm(acc[3], A3, bfr);
        BAR();
    }
    {   // tile NT-1: no staging, no vmcnt
        const int b = (NT - 1) & 1;
        const bf16* Asb = smem[b];
        const bf16* Bsb = smem[b] + 16384;
        bf16x8 bfr[4][2], A0[2][2], A1[2][2], A2[2][2], A3[2][2];
        ldb4(bfr, Bsb);
        lda2(A0, Asb, 0);
        BAR(); LGKM0(); SCHED0();
        mm(acc[0], A0, bfr);
        BAR();
        lda2(A1, Asb, 2);
        lda2(A2, Asb, 4);
        BAR(); LGKM0(); SCHED0();
        mm(acc[1], A1, bfr);
        BAR();
        lda2(A3, Asb, 6);
        BAR(); LGKM0(); SCHED0();
        mm(acc[2], A2, bfr);
        mm(acc[3], A3, bfr);     // A3 covered by the LGKM0 above
    }

    // epilogue: C/D map col=lane&15, row=quad*4+reg
    #pragma unroll
    for (int q2 = 0; q2 < 4; ++q2)
        #pragma unroll
        for (int f = 0; f < 2; ++f)
            #pragma unroll
            for (int n = 0; n < 4; ++n) {
                const int c  = n0 + wn + n * 16 + col16;
                const int rb = m0 + wm + (q2 * 2 + f) * 16 + quad * 4;
                #pragma unroll
                for (int r = 0; r < 4; ++r) {
                    size_t off = (size_t)(rb + r) * N + c;
                    float v = acc[q2][f][n][r];
                    if (RESID) {
                        Fout[off] = resid[off] + scale[c] * v;
                    } else {
                        Hout[off] = (bf16)v;
                    }
                }
            }
}

extern "C" void kernel_launch(void* const* d_in, const int* in_sizes, int n_in,
                              void* d_out, int out_size, void* d_ws, size_t ws_size,
                              hipStream_t stream) {
    const float* x  = (const float*)d_in[0];
    const float* We = (const float*)d_in[1];
    const float* cw = (const float*)d_in[2];
    const float* cb = (const float*)d_in[3];
    const float* Wp = (const float*)d_in[4];
    const float* cs = (const float*)d_in[5];
    const int*   dil = (const int*)d_in[6];

    char* ws = (char*)d_ws;
    bf16* xn  = (bf16*)ws;                                  // 67108864 B (reused for o)
    bf16* Web = (bf16*)(ws + 67108864);                     // 25165824 B
    bf16* Wpb = (bf16*)(ws + 67108864 + 25165824);          // 8388608 B
    bf16* h   = (bf16*)(ws + 100663296);                    // 201326592 B

    f2bf_k<<<(3 * DIMD * DIMD / 4 + 255) / 256, 256, 0, stream>>>(We, Web, 3 * DIMD * DIMD);
    f2bf_k<<<(DIMD * DIMD / 4 + 255) / 256, 256, 0, stream>>>(Wp, Wpb, DIMD * DIMD);
    rmsnorm_k<<<MTOT, 256, 0, stream>>>(x, xn);
    gemm_bt<0><<<dim3(3 * DIMD / 256, MTOT / 256), 512, 0, stream>>>(
        xn, Web, h, nullptr, nullptr, nullptr, MTOT, 3 * DIMD, DIMD);
    gateconv_k<<<(MTOT * (DIMD / 4)) / 256, 256, 0, stream>>>(h, cw, cb, xn /*o*/, dil);
    gemm_bt<1><<<dim3(DIMD / 256, MTOT / 256), 512, 0, stream>>>(
        xn /*o*/, Wpb, nullptr, (float*)d_out, x, cs, MTOT, DIMD, DIMD);
}